// Round 7
// baseline (86.347 us; speedup 1.0000x reference)
//
#include <hip/hip_runtime.h>
#include <hip/hip_bf16.h>

typedef unsigned short u16;
typedef unsigned int u32;
typedef __bf16 bf16x8 __attribute__((ext_vector_type(8)));
typedef float floatx4 __attribute__((ext_vector_type(4)));

#define MFMA16(a,b,c) __builtin_amdgcn_mfma_f32_16x16x32_bf16((a),(b),(c),0,0,0)
#define AS1 __attribute__((address_space(1)))
#define AS3 __attribute__((address_space(3)))
#define VM12 asm volatile("s_waitcnt vmcnt(12)" ::: "memory")
#define VM8  asm volatile("s_waitcnt vmcnt(8)" ::: "memory")
#define VM6  asm volatile("s_waitcnt vmcnt(6)" ::: "memory")
#define VM4  asm volatile("s_waitcnt vmcnt(4)" ::: "memory")
#define VM0  asm volatile("s_waitcnt vmcnt(0)" ::: "memory")
#define SBAR __builtin_amdgcn_s_barrier()
#define SCHED0 __builtin_amdgcn_sched_barrier(0)

__device__ __forceinline__ void gl16(const void* g, void* l){
  __builtin_amdgcn_global_load_lds((const AS1 void*)g, (AS3 void*)l, 16, 0, 0);
}

__device__ __forceinline__ u16 f2bf(float f){
  u32 u = __builtin_bit_cast(u32, f);
  u += 0x7FFFu + ((u >> 16) & 1u);
  return (u16)(u >> 16);
}
__device__ __forceinline__ float bf2f(u16 h){
  u32 u = ((u32)h) << 16;
  return __builtin_bit_cast(float, u);
}
__device__ __forceinline__ bf16x8 ldfrag(const u16* p){
  return *(const bf16x8*)p;
}

// ================ KX: X staging + weight prep + zero sums ===================
// blk [0,256): X staging (blk<128 also zero sums); [256,544): weight prep
__global__ __launch_bounds__(256) void kx_pre(
    const float* __restrict__ inp, const float* __restrict__ hx,
    const float* __restrict__ W0, const float* __restrict__ b0,
    const float* __restrict__ W1, const float* __restrict__ b1,
    const float* __restrict__ Wc0, const float* __restrict__ bc0,
    const float* __restrict__ Wc1, const float* __restrict__ bc1,
    u16* __restrict__ WgT, u16* __restrict__ WcT,
    float* __restrict__ bias_g, float* __restrict__ bias_c,
    float* __restrict__ sums /*colsum|rowsum 32768 f32*/,
    u16* __restrict__ Xt, u16* __restrict__ XC2){
  __shared__ u16 XT[128][80];
  int t = threadIdx.x;
  int blk = blockIdx.x;
  if (blk >= 256) {
    int id = (blk - 256)*256 + t;
    if (id < 128*384) {
      int n = id / 384, k = id % 384;
      float v;
      if (k < 128)       v = W0[(k*3+0)*128 + n] + W1[(k*3+0)*128 + n];
      else if (k < 256){ int f = k-128; v = W0[(f*3+1)*128+n] + W0[(f*3+2)*128+n]; }
      else             { int f = k-256; v = W1[(f*3+1)*128+n] + W1[(f*3+2)*128+n]; }
      WgT[(size_t)n*384 + k] = f2bf(v);
    } else {
      int id2 = id - 128*384;
      int n = id2 / 384, k = id2 % 384;
      float v;
      if (k < 128)       v = Wc0[(k*3+0)*64 + n] + Wc1[(k*3+0)*64 + n];
      else if (k < 256){ int f = k-128; v = Wc0[(f*3+1)*64+n] + Wc0[(f*3+2)*64+n]; }
      else             { int f = k-256; v = Wc1[(f*3+1)*64+n] + Wc1[(f*3+2)*64+n]; }
      WcT[(size_t)n*384 + k] = f2bf(v);
    }
    if (blk == 256) {
      if (t < 128) bias_g[t] = b0[t] + b1[t];
      if (t < 64)  bias_c[t] = bc0[t] + bc1[t];
    }
    return;
  }
  if (blk < 128) sums[blk*256 + t] = 0.0f;   // zero colsum+rowsum
  int r = t >> 2;
  int row = blk*64 + r;
  int fq = t & 3;
  const float4* ip = (const float4*)(inp + (size_t)row*64 + fq*16);
  const float4* hp = (const float4*)(hx  + (size_t)row*64 + fq*16);
  float iv[16], hv[16];
  #pragma unroll
  for (int q=0;q<4;q++){
    float4 a = ip[q]; iv[4*q]=a.x; iv[4*q+1]=a.y; iv[4*q+2]=a.z; iv[4*q+3]=a.w;
    float4 c = hp[q]; hv[4*q]=c.x; hv[4*q+1]=c.y; hv[4*q+2]=c.z; hv[4*q+3]=c.w;
  }
  u16 ib[16], hb[16];
  #pragma unroll
  for (int q=0;q<16;q++){ ib[q]=f2bf(iv[q]); hb[q]=f2bf(hv[q]); }
  u32 pi[8];
  #pragma unroll
  for (int q=0;q<8;q++) pi[q] = (u32)ib[2*q] | ((u32)ib[2*q+1]<<16);
  size_t rbase = (size_t)row*384;
  *(uint4*)(XC2 + rbase + fq*16)     = make_uint4(pi[0],pi[1],pi[2],pi[3]);
  *(uint4*)(XC2 + rbase + fq*16 + 8) = make_uint4(pi[4],pi[5],pi[6],pi[7]);
  #pragma unroll
  for (int q=0;q<16;q++){
    XT[fq*16+q][r]    = ib[q];
    XT[64+fq*16+q][r] = hb[q];
  }
  __syncthreads();
  int feat = t >> 1, half = t & 1;
  int b = blk >> 4, n0 = (blk & 15)*64;
  const uint4* src = (const uint4*)&XT[feat][half*32];
  uint4* dst = (uint4*)(Xt + (size_t)b*131072 + (size_t)feat*1024 + n0 + half*32);
  dst[0]=src[0]; dst[1]=src[1]; dst[2]=src[2]; dst[3]=src[3];
}

// ================ KP2: adj convert + transpose + sums; 1024 uniform blocks ==
// blk -> (b, stripe of 64 rows, quarter of 4 col-chunks)
__global__ __launch_bounds__(256) void kp2_adj(const float* __restrict__ adj,
    u16* __restrict__ adjbf, u16* __restrict__ adjTbf,
    float* __restrict__ colsum, float* __restrict__ rowsum){
  __shared__ u16 lt[2][64][72];
  int t = threadIdx.x, r = t >> 2, cq = t & 3;
  int blk = blockIdx.x;
  int b = blk >> 6, st = (blk >> 2) & 15, h = blk & 3;
  int i0 = st*64;
  size_t base = (size_t)b << 20;
  float rowacc = 0.f;
  for (int c = h*4; c < h*4+4; ++c){
    int j0 = c*64, cb = c & 1;
    const float4* s4 = (const float4*)(adj + base + (size_t)(i0 + r)*1024 + j0 + (cq<<4));
    float v[16];
    #pragma unroll
    for (int q = 0; q < 4; q++) {
      float4 f = s4[q];
      v[4*q]=f.x; v[4*q+1]=f.y; v[4*q+2]=f.z; v[4*q+3]=f.w;
    }
    u32 u8[8];
    #pragma unroll
    for (int q = 0; q < 8; q++)
      u8[q] = (u32)f2bf(v[2*q]) | ((u32)f2bf(v[2*q+1]) << 16);
    uint4* d = (uint4*)(adjbf + base + (size_t)(i0 + r)*1024 + j0 + (cq<<4));
    d[0] = make_uint4(u8[0],u8[1],u8[2],u8[3]);
    d[1] = make_uint4(u8[4],u8[5],u8[6],u8[7]);
    #pragma unroll
    for (int q = 0; q < 16; q++) rowacc += v[q];
    #pragma unroll
    for (int q = 0; q < 16; q++)
      lt[cb][(cq<<4) + q][r] = (u16)(u8[q>>1] >> ((q&1)*16));
    __syncthreads();
    uint4 q0 = *(const uint4*)&lt[cb][r][(cq<<4)];
    uint4 q1 = *(const uint4*)&lt[cb][r][(cq<<4) + 8];
    uint4* dT = (uint4*)(adjTbf + base + (size_t)(j0 + r)*1024 + i0 + (cq<<4));
    dT[0] = q0; dT[1] = q1;
    u32 w8[8] = {q0.x,q0.y,q0.z,q0.w,q1.x,q1.y,q1.z,q1.w};
    float cs = 0.f;
    #pragma unroll
    for (int q = 0; q < 8; q++)
      cs += bf2f((u16)(w8[q] & 0xFFFFu)) + bf2f((u16)(w8[q] >> 16));
    cs += __shfl_down(cs, 1, 64);
    cs += __shfl_down(cs, 2, 64);
    if (cq == 0) atomicAdd(&colsum[b*1024 + j0 + r], cs);
  }
  rowacc += __shfl_down(rowacc, 1, 64);
  rowacc += __shfl_down(rowacc, 2, 64);
  if (cq == 0) atomicAdd(&rowsum[b*1024 + i0 + r], rowacc);
}

// ================ KG: both-direction diffusion + gates; 3-stage pipeline ====
__global__ __launch_bounds__(256) void kg_gates(
    const u16* __restrict__ adjbf, const u16* __restrict__ adjTbf,
    const u16* __restrict__ Xt,
    const float* __restrict__ inp, const float* __restrict__ hx,
    const float* __restrict__ colsum, const float* __restrict__ rowsum,
    const u16* __restrict__ WgT, const float* __restrict__ bias_g,
    u16* __restrict__ XC2, u16* __restrict__ St, u16* __restrict__ uBuf){
  __shared__ __align__(16) u16 lds[36864];   // 72 KB: A0 3x4K | A1 3x4K | B 3x16K
  char* ldsb = (char*)lds;
  int bid0 = blockIdx.x;
  int bid = (bid0 & 7)*64 + (bid0 >> 3);     // XCD swizzle, 512 = 8*64
  int mt = bid & 31, b = bid >> 5;
  const u16* A0 = adjbf  + ((size_t)b<<20) + (size_t)mt*32*1024;
  const u16* A1 = adjTbf + ((size_t)b<<20) + (size_t)mt*32*1024;
  const u16* Xb = Xt + (size_t)b*131072;
  int t = threadIdx.x, w = t>>6, l = t&63, lr = l&15, lg = l>>4;
  int wm = w>>1, wn = w&1;
  int swz = ((l&7) ^ ((l>>3)&7)) << 4;
  const char* A0g = (const char*)A0 + (size_t)(w*8  + (l>>3))*2048 + swz;
  const char* A1g = (const char*)A1 + (size_t)(w*8  + (l>>3))*2048 + swz;
  const char* Bg  = (const char*)Xb + (size_t)(w*32 + (l>>3))*2048 + swz;
  floatx4 acc0[4] = {}, acc1[4] = {};
  #define STG_KG(bufi, kk) do{ \
    gl16(A0g + (size_t)(kk)*2, ldsb + (bufi)*4096 + w*1024); \
    gl16(A1g + (size_t)(kk)*2, ldsb + 12288 + (bufi)*4096 + w*1024); \
    gl16(Bg + 0*16384 + (size_t)(kk)*2, ldsb + 24576 + (bufi)*16384 + w*4096 + 0*1024); \
    gl16(Bg + 1*16384 + (size_t)(kk)*2, ldsb + 24576 + (bufi)*16384 + w*4096 + 1*1024); \
    gl16(Bg + 2*16384 + (size_t)(kk)*2, ldsb + 24576 + (bufi)*16384 + w*4096 + 2*1024); \
    gl16(Bg + 3*16384 + (size_t)(kk)*2, ldsb + 24576 + (bufi)*16384 + w*4096 + 3*1024); \
  }while(0)
  STG_KG(0, 0);
  STG_KG(1, 64);
  int cur = 0;
  for (int step = 0; step < 16; ++step){
    if (step < 14) {
      int nb = cur + 2; if (nb >= 3) nb -= 3;
      STG_KG(nb, (step+2)*64);
      VM12;
    } else if (step == 14) { VM6; } else { VM0; }
    SBAR; SCHED0;
    const char* A0b = ldsb + cur*4096;
    const char* A1b = ldsb + 12288 + cur*4096;
    const char* Bb  = ldsb + 24576 + cur*16384;
    #pragma unroll
    for (int kf=0; kf<2; kf++){
      int fo = (kf*64 + lg*16) ^ ((lr&7)<<4);
      bf16x8 a0 = *(const bf16x8*)(A0b + (wm*16+lr)*128 + fo);
      bf16x8 a1 = *(const bf16x8*)(A1b + (wm*16+lr)*128 + fo);
      #pragma unroll
      for (int nf=0; nf<4; nf++){
        bf16x8 bb = *(const bf16x8*)(Bb + (wn*64+nf*16+lr)*128 + fo);
        acc0[nf] = MFMA16(a0, bb, acc0[nf]);
        acc1[nf] = MFMA16(a1, bb, acc1[nf]);
      }
    }
    SCHED0; SBAR;
    if (++cur == 3) cur = 0;
  }
  __syncthreads();
  // ---- epilogue: SL[32][392] = [x(128) | Y0(128) | Y1(128)] ----
  u16* SL = lds;                 // 12544 u16
  u16* SLT = lds + 12544;        // [64][40]
  float d0i[4], d1i[4];
  #pragma unroll
  for (int rr=0; rr<4; rr++){
    int row = mt*32 + wm*16 + lg*4 + rr;
    d0i[rr] = 1.0f / (colsum[b*1024 + row] + 1.0f);
    d1i[rr] = 1.0f / (rowsum[b*1024 + row] + 1.0f);
  }
  #pragma unroll
  for (int nf = 0; nf < 4; nf++) {
    #pragma unroll
    for (int rr = 0; rr < 4; rr++) {
      int rl = wm*16 + lg*4 + rr;
      int row = mt*32 + rl;
      int col = wn*64 + nf*16 + lr;
      float xv = (col < 64) ? inp[(size_t)(b*1024+row)*64 + col]
                            : hx [(size_t)(b*1024+row)*64 + (col-64)];
      float y0 = (acc0[nf][rr] + xv) * d0i[rr];
      float y1 = (acc1[nf][rr] + xv) * d1i[rr];
      u16 b0v = f2bf(y0), b1v = f2bf(y1);
      SL[rl*392 + col]       = f2bf(xv);
      SL[rl*392 + 128 + col] = b0v;
      SL[rl*392 + 256 + col] = b1v;
      if (col < 64) {
        size_t grow = (size_t)(b*1024 + row)*384;
        XC2[grow + 128 + col] = b0v;
        XC2[grow + 256 + col] = b1v;
      }
    }
  }
  __syncthreads();
  // ---- gates GEMM: 32x384 @ 384x128 ----
  floatx4 g[4] = {};
  for (int kk = 0; kk < 384; kk += 32) {
    int ko = kk + lg*8;
    bf16x8 a = ldfrag(&SL[(size_t)(wm*16+lr)*392 + ko]);
    #pragma unroll
    for (int nf = 0; nf < 4; nf++)
      g[nf] = MFMA16(a, ldfrag(WgT + (size_t)(wn*64+nf*16+lr)*384 + ko), g[nf]);
  }
  #pragma unroll
  for (int nf = 0; nf < 4; nf++) {
    #pragma unroll
    for (int rr = 0; rr < 4; rr++) {
      int rl = wm*16 + lg*4 + rr;
      int row = mt*32 + rl;
      int col = wn*64 + nf*16 + lr;
      float pre = g[nf][rr] + bias_g[col];
      float s = 1.0f / (1.0f + __expf(-pre));
      if (col < 64) {          // r gate
        float sh = s * hx[(size_t)(b*1024+row)*64 + col];
        u16 bv = f2bf(sh);
        XC2[(size_t)(b*1024+row)*384 + 64 + col] = bv;
        SLT[col*40 + rl] = bv;
      } else {                 // u gate
        uBuf[(size_t)(b*1024+row)*64 + (col-64)] = f2bf(s);
      }
    }
  }
  __syncthreads();
  {
    int c2 = t >> 2, q = t & 3;
    uint4 vv = *(const uint4*)&SLT[c2*40 + q*8];
    *(uint4*)(St + (size_t)b*65536 + (size_t)c2*1024 + mt*32 + q*8) = vv;
  }
  #undef STG_KG
}

// ================ KZ: both-direction Z diffusion + candidate + GRU ==========
__global__ __launch_bounds__(256) void kz_cand(
    const u16* __restrict__ adjbf, const u16* __restrict__ adjTbf,
    const u16* __restrict__ St,
    const float* __restrict__ colsum, const float* __restrict__ rowsum,
    const u16* __restrict__ XC2, const u16* __restrict__ WcT,
    const float* __restrict__ bias_c,
    const u16* __restrict__ uBuf, const float* __restrict__ hx,
    float* __restrict__ out){
  __shared__ __align__(16) u16 lds[24576];   // 48 KB: A0 3x4K | A1 3x4K | B 3x8K
  char* ldsb = (char*)lds;
  int bid0 = blockIdx.x;
  int bid = (bid0 & 7)*64 + (bid0 >> 3);
  int mt = bid & 31, b = bid >> 5;
  const u16* A0 = adjbf  + ((size_t)b<<20) + (size_t)mt*32*1024;
  const u16* A1 = adjTbf + ((size_t)b<<20) + (size_t)mt*32*1024;
  const u16* Sb = St + (size_t)b*65536;
  int t = threadIdx.x, w = t>>6, l = t&63, lr = l&15, lg = l>>4;
  int wm = w>>1, wn = w&1;
  int swz = ((l&7) ^ ((l>>3)&7)) << 4;
  const char* A0g = (const char*)A0 + (size_t)(w*8  + (l>>3))*2048 + swz;
  const char* A1g = (const char*)A1 + (size_t)(w*8  + (l>>3))*2048 + swz;
  const char* Bg  = (const char*)Sb + (size_t)(w*16 + (l>>3))*2048 + swz;
  floatx4 z0[2] = {}, z1[2] = {};
  #define STG_KZ(bufi, kk) do{ \
    gl16(A0g + (size_t)(kk)*2, ldsb + (bufi)*4096 + w*1024); \
    gl16(A1g + (size_t)(kk)*2, ldsb + 12288 + (bufi)*4096 + w*1024); \
    gl16(Bg + 0*16384 + (size_t)(kk)*2, ldsb + 24576 + (bufi)*8192 + w*2048 + 0*1024); \
    gl16(Bg + 1*16384 + (size_t)(kk)*2, ldsb + 24576 + (bufi)*8192 + w*2048 + 1*1024); \
  }while(0)
  STG_KZ(0, 0);
  STG_KZ(1, 64);
  int cur = 0;
  for (int step = 0; step < 16; ++step){
    if (step < 14) {
      int nb = cur + 2; if (nb >= 3) nb -= 3;
      STG_KZ(nb, (step+2)*64);
      VM8;
    } else if (step == 14) { VM4; } else { VM0; }
    SBAR; SCHED0;
    const char* A0b = ldsb + cur*4096;
    const char* A1b = ldsb + 12288 + cur*4096;
    const char* Bb  = ldsb + 24576 + cur*8192;
    #pragma unroll
    for (int kf=0; kf<2; kf++){
      int fo = (kf*64 + lg*16) ^ ((lr&7)<<4);
      bf16x8 a0 = *(const bf16x8*)(A0b + (wm*16+lr)*128 + fo);
      bf16x8 a1 = *(const bf16x8*)(A1b + (wm*16+lr)*128 + fo);
      #pragma unroll
      for (int nf=0; nf<2; nf++){
        bf16x8 bb = *(const bf16x8*)(Bb + (wn*32+nf*16+lr)*128 + fo);
        z0[nf] = MFMA16(a0, bb, z0[nf]);
        z1[nf] = MFMA16(a1, bb, z1[nf]);
      }
    }
    SCHED0; SBAR;
    if (++cur == 3) cur = 0;
  }
  __syncthreads();
  // ---- SL[32][392] = [x|S | Y0inp|Z0 | Y1inp|Z1] ----
  u16* SL = lds;
  {
    int rl = t >> 3, s = t & 7;
    size_t grow = (size_t)(b*1024 + mt*32 + rl)*384;
    #pragma unroll
    for (int j = 0; j < 3; j++)
      *(uint4*)&SL[(size_t)rl*392 + s*24 + j*8] =
        *(const uint4*)(XC2 + grow + s*24 + j*8);
    *(uint4*)&SL[(size_t)rl*392 + 256 + s*8] =
      *(const uint4*)(XC2 + grow + 256 + s*8);
  }
  float d0i[4], d1i[4];
  #pragma unroll
  for (int rr=0; rr<4; rr++){
    int row = mt*32 + wm*16 + lg*4 + rr;
    d0i[rr] = 1.0f / (colsum[b*1024 + row] + 1.0f);
    d1i[rr] = 1.0f / (rowsum[b*1024 + row] + 1.0f);
  }
  #pragma unroll
  for (int nf = 0; nf < 2; nf++) {
    #pragma unroll
    for (int rr = 0; rr < 4; rr++) {
      int rl = wm*16 + lg*4 + rr;
      int row = mt*32 + rl;
      int col = wn*32 + nf*16 + lr;
      float sval = bf2f(XC2[(size_t)(b*1024+row)*384 + 64 + col]);
      SL[rl*392 + 192 + col] = f2bf((z0[nf][rr] + sval) * d0i[rr]);
      SL[rl*392 + 320 + col] = f2bf((z1[nf][rr] + sval) * d1i[rr]);
    }
  }
  __syncthreads();
  floatx4 c[2] = {};
  for (int kk = 0; kk < 384; kk += 32) {
    int ko = kk + lg*8;
    bf16x8 a = ldfrag(&SL[(size_t)(wm*16+lr)*392 + ko]);
    #pragma unroll
    for (int nf = 0; nf < 2; nf++)
      c[nf] = MFMA16(a, ldfrag(WcT + (size_t)(wn*32+nf*16+lr)*384 + ko), c[nf]);
  }
  #pragma unroll
  for (int nf = 0; nf < 2; nf++) {
    #pragma unroll
    for (int rr = 0; rr < 4; rr++) {
      int row = mt*32 + wm*16 + lg*4 + rr;
      int col = wn*32 + nf*16 + lr;
      float pre = c[nf][rr] + bias_c[col];
      pre = fminf(fmaxf(pre, -15.f), 15.f);
      float e2 = __expf(2.0f*pre);
      float cv = (e2 - 1.0f) / (e2 + 1.0f);
      float u = bf2f(uBuf[(size_t)(b*1024+row)*64 + col]);
      float h = hx[(size_t)(b*1024+row)*64 + col];
      out[(size_t)(b*1024+row)*64 + col] = u*h + (1.0f - u)*cv;
    }
  }
  #undef STG_KZ
}

extern "C" void kernel_launch(void* const* d_in, const int* in_sizes, int n_in,
                              void* d_out, int out_size, void* d_ws, size_t ws_size,
                              hipStream_t stream) {
  (void)in_sizes; (void)n_in; (void)out_size; (void)ws_size;
  const float* inp = (const float*)d_in[0];
  const float* hx  = (const float*)d_in[1];
  const float* adj = (const float*)d_in[2];
  const float* W0  = (const float*)d_in[3];
  const float* b0  = (const float*)d_in[4];
  const float* W1  = (const float*)d_in[5];
  const float* b1  = (const float*)d_in[6];
  const float* Wc0 = (const float*)d_in[7];
  const float* bc0 = (const float*)d_in[8];
  const float* Wc1 = (const float*)d_in[9];
  const float* bc1 = (const float*)d_in[10];
  float* out = (float*)d_out;
  char* ws = (char*)d_ws;

  float* colsum = (float*)(ws + 0);
  float* rowsum = (float*)(ws + 65536);
  u16* adjbf  = (u16*)(ws + 131072);
  u16* adjTbf = (u16*)(ws + 33685504);
  u16* Xt     = (u16*)(ws + 67239936);
  u16* XC2    = (u16*)(ws + 84017152);
  u16* St     = (u16*)(ws + 96600064);
  u16* uBuf   = (u16*)(ws + 98697216);
  u16* WgT    = (u16*)(ws + 102891520);
  u16* WcT    = (u16*)(ws + 102989824);
  float* bias_g = (float*)(ws + 103038976);
  float* bias_c = (float*)(ws + 103039488);

  hipLaunchKernelGGL(kx_pre, dim3(544), dim3(256), 0, stream,
                     inp, hx, W0, b0, W1, b1, Wc0, bc0, Wc1, bc1,
                     WgT, WcT, bias_g, bias_c, colsum, Xt, XC2);
  hipLaunchKernelGGL(kp2_adj, dim3(1024), dim3(256), 0, stream,
                     adj, adjbf, adjTbf, colsum, rowsum);
  hipLaunchKernelGGL(kg_gates, dim3(512), dim3(256), 0, stream,
                     adjbf, adjTbf, Xt, inp, hx, colsum, rowsum,
                     WgT, bias_g, XC2, St, uBuf);
  hipLaunchKernelGGL(kz_cand, dim3(512), dim3(256), 0, stream,
                     adjbf, adjTbf, St, colsum, rowsum,
                     XC2, WcT, bias_c, uBuf, hx, out);
}

// Round 8
// 74.827 us; speedup vs baseline: 1.1539x; 1.1539x over previous
//
#include <hip/hip_runtime.h>
#include <hip/hip_bf16.h>

typedef unsigned short u16;
typedef unsigned int u32;
typedef unsigned char u8;
typedef long i64;
typedef __bf16 bf16x8 __attribute__((ext_vector_type(8)));
typedef float floatx4 __attribute__((ext_vector_type(4)));

#define MFMA16(a,b,c) __builtin_amdgcn_mfma_f32_16x16x32_bf16((a),(b),(c),0,0,0)
#define MFMA8(a,b,c)  __builtin_amdgcn_mfma_f32_16x16x32_fp8_fp8((a),(b),(c),0,0,0)
#define AS1 __attribute__((address_space(1)))
#define AS3 __attribute__((address_space(3)))
#define VM6 asm volatile("s_waitcnt vmcnt(6)" ::: "memory")
#define VM4 asm volatile("s_waitcnt vmcnt(4)" ::: "memory")
#define VM3 asm volatile("s_waitcnt vmcnt(3)" ::: "memory")
#define VM2 asm volatile("s_waitcnt vmcnt(2)" ::: "memory")
#define VM0 asm volatile("s_waitcnt vmcnt(0)" ::: "memory")
#define SBAR __builtin_amdgcn_s_barrier()
#define SCHED0 __builtin_amdgcn_sched_barrier(0)

__device__ __forceinline__ void gl16(const void* g, void* l){
  __builtin_amdgcn_global_load_lds((const AS1 void*)g, (AS3 void*)l, 16, 0, 0);
}
__device__ __forceinline__ u16 f2bf(float f){
  u32 u = __builtin_bit_cast(u32, f);
  u += 0x7FFFu + ((u >> 16) & 1u);
  return (u16)(u >> 16);
}
__device__ __forceinline__ float bf2f(u16 h){
  u32 u = ((u32)h) << 16;
  return __builtin_bit_cast(float, u);
}
__device__ __forceinline__ bf16x8 ldfrag(const u16* p){
  return *(const bf16x8*)p;
}
__device__ __forceinline__ u32 pk4(float a, float b, float c, float d){
  int r = __builtin_amdgcn_cvt_pk_fp8_f32(a, b, 0, false);
  r = __builtin_amdgcn_cvt_pk_fp8_f32(c, d, r, true);
  return (u32)r;
}
// swizzled fp8 fragment read: chunk rows of 64B, superrow(2 rows)=128B, 16B-granule XOR
__device__ __forceinline__ i64 ldA8(const char* chunk, int r, int kf, int lg){
  int sr = r >> 1;
  int G = (((r&1)<<2) + (kf<<1) + (lg>>1)) ^ (sr&7);
  return *(const i64*)(chunk + sr*128 + G*16 + (lg&1)*8);
}

// ================ KP3: X staging + weight prep + adj fp8 convert ============
// blk [0,256): X; [256,544): weights; [544,1568): adj tiles
__global__ __launch_bounds__(256) void kp3_prep(
    const float* __restrict__ inp, const float* __restrict__ hx,
    const float* __restrict__ adj,
    const float* __restrict__ W0, const float* __restrict__ b0,
    const float* __restrict__ W1, const float* __restrict__ b1,
    const float* __restrict__ Wc0, const float* __restrict__ bc0,
    const float* __restrict__ Wc1, const float* __restrict__ bc1,
    u16* __restrict__ WgT, u16* __restrict__ WcT,
    float* __restrict__ bias_g, float* __restrict__ bias_c,
    u8* __restrict__ adjf8, u8* __restrict__ adjTf8,
    u8* __restrict__ Xtf8, u16* __restrict__ XC2){
  __shared__ __align__(16) char sh[40960];
  int t = threadIdx.x;
  int blk = blockIdx.x;
  if (blk < 256) {
    // ---- X staging: XC2 x-cols bf16 + Xtf8 feature-major fp8 ----
    float (*XT)[80] = (float(*)[80])sh;
    int r = t >> 2;
    int row = blk*64 + r;
    int fq = t & 3;
    const float4* ip = (const float4*)(inp + (size_t)row*64 + fq*16);
    const float4* hp = (const float4*)(hx  + (size_t)row*64 + fq*16);
    float iv[16], hv[16];
    #pragma unroll
    for (int q=0;q<4;q++){
      float4 a = ip[q]; iv[4*q]=a.x; iv[4*q+1]=a.y; iv[4*q+2]=a.z; iv[4*q+3]=a.w;
      float4 c = hp[q]; hv[4*q]=c.x; hv[4*q+1]=c.y; hv[4*q+2]=c.z; hv[4*q+3]=c.w;
    }
    u32 pi[8];
    #pragma unroll
    for (int q=0;q<8;q++)
      pi[q] = (u32)f2bf(iv[2*q]) | ((u32)f2bf(iv[2*q+1])<<16);
    size_t rbase = (size_t)row*384;
    *(uint4*)(XC2 + rbase + fq*16)     = make_uint4(pi[0],pi[1],pi[2],pi[3]);
    *(uint4*)(XC2 + rbase + fq*16 + 8) = make_uint4(pi[4],pi[5],pi[6],pi[7]);
    #pragma unroll
    for (int q=0;q<16;q++){
      XT[fq*16+q][r]    = iv[q];
      XT[64+fq*16+q][r] = hv[q];
    }
    __syncthreads();
    int feat = t >> 1, half = t & 1;
    int b = blk >> 4, n0 = (blk & 15)*64;
    const float* src = &XT[feat][half*32];
    u32 o[8];
    #pragma unroll
    for (int p=0;p<8;p++)
      o[p] = pk4(src[4*p],src[4*p+1],src[4*p+2],src[4*p+3]);
    u8* dst = Xtf8 + (size_t)b*131072 + (size_t)feat*1024 + n0 + half*32;
    *(uint4*)dst      = make_uint4(o[0],o[1],o[2],o[3]);
    *(uint4*)(dst+16) = make_uint4(o[4],o[5],o[6],o[7]);
    return;
  }
  if (blk < 544) {
    int id = (blk - 256)*256 + t;
    if (id < 128*384) {
      int n = id / 384, k = id % 384;
      float v;
      if (k < 128)       v = W0[(k*3+0)*128 + n] + W1[(k*3+0)*128 + n];
      else if (k < 256){ int f = k-128; v = W0[(f*3+1)*128+n] + W0[(f*3+2)*128+n]; }
      else             { int f = k-256; v = W1[(f*3+1)*128+n] + W1[(f*3+2)*128+n]; }
      WgT[(size_t)n*384 + k] = f2bf(v);
    } else {
      int id2 = id - 128*384;
      int n = id2 / 384, k = id2 % 384;
      float v;
      if (k < 128)       v = Wc0[(k*3+0)*64 + n] + Wc1[(k*3+0)*64 + n];
      else if (k < 256){ int f = k-128; v = Wc0[(f*3+1)*64+n] + Wc0[(f*3+2)*64+n]; }
      else             { int f = k-256; v = Wc1[(f*3+1)*64+n] + Wc1[(f*3+2)*64+n]; }
      WcT[(size_t)n*384 + k] = f2bf(v);
    }
    if (blk == 256) {
      if (t < 128) bias_g[t] = b0[t] + b1[t];
      if (t < 64)  bias_c[t] = bc0[t] + bc1[t];
    }
    return;
  }
  // ---- adj: f32 -> fp8 copy + transposed fp8 copy (byte transpose in LDS) ----
  u8* ltb = (u8*)sh;                 // lt[2][64][72] bytes
  int blk2 = blk - 544;
  int b = blk2 >> 6, st = (blk2 >> 2) & 15, h = blk2 & 3;
  int i0 = st*64;
  int r = t >> 2, cq = t & 3;
  size_t base = (size_t)b << 20;
  for (int c = h*4; c < h*4+4; ++c){
    int j0 = c*64, cb = c & 1;
    const float4* s4 = (const float4*)(adj + base + (size_t)(i0 + r)*1024 + j0 + (cq<<4));
    float v[16];
    #pragma unroll
    for (int q = 0; q < 4; q++) {
      float4 f = s4[q];
      v[4*q]=f.x; v[4*q+1]=f.y; v[4*q+2]=f.z; v[4*q+3]=f.w;
    }
    u32 pk[4];
    #pragma unroll
    for (int p = 0; p < 4; p++)
      pk[p] = pk4(v[4*p],v[4*p+1],v[4*p+2],v[4*p+3]);
    *(uint4*)(adjf8 + base + (size_t)(i0 + r)*1024 + j0 + (cq<<4)) =
      make_uint4(pk[0],pk[1],pk[2],pk[3]);
    #pragma unroll
    for (int q = 0; q < 16; q++)
      ltb[cb*4608 + (cq*16+q)*72 + r] = (u8)(pk[q>>2] >> ((q&3)*8));
    __syncthreads();
    u32 w4[4];
    #pragma unroll
    for (int p = 0; p < 4; p++){
      u32 b0v = ltb[cb*4608 + r*72 + cq*16 + 4*p];
      u32 b1v = ltb[cb*4608 + r*72 + cq*16 + 4*p+1];
      u32 b2v = ltb[cb*4608 + r*72 + cq*16 + 4*p+2];
      u32 b3v = ltb[cb*4608 + r*72 + cq*16 + 4*p+3];
      w4[p] = b0v | (b1v<<8) | (b2v<<16) | (b3v<<24);
    }
    *(uint4*)(adjTf8 + base + (size_t)(j0 + r)*1024 + i0 + (cq<<4)) =
      make_uint4(w4[0],w4[1],w4[2],w4[3]);
  }
}

// ================ KG2: fp8 both-direction diffusion + gates =================
__global__ __launch_bounds__(256) void kg2_gates(
    const u8* __restrict__ adjf8, const u8* __restrict__ adjTf8,
    const u8* __restrict__ Xtf8,
    const float* __restrict__ inp, const float* __restrict__ hx,
    const u16* __restrict__ WgT, const float* __restrict__ bias_g,
    u16* __restrict__ XC2, u8* __restrict__ Stf8, float* __restrict__ uBuf){
  __shared__ __align__(16) char lds[36864];  // A0 3x2K | A1 @6144 3x2K | B @12288 3x8K
  int bid = ((blockIdx.x & 7)<<6) + (blockIdx.x >> 3);
  int mt = bid & 31, b = bid >> 5;
  int t = threadIdx.x, w = t>>6, l = t&63, lr = l&15, lg = l>>4;
  int wm = w>>1, wn = w&1;
  int gp = (l&7) ^ ((l>>3)&7);
  size_t off = (size_t)(2*(l>>3) + (gp>>2))*1024 + (gp&3)*16;
  const u8* A0g = adjf8  + ((size_t)b<<20) + (size_t)mt*32768 + off;
  const u8* A1g = adjTf8 + ((size_t)b<<20) + (size_t)mt*32768 + off;
  const u8* Bg  = Xtf8 + (size_t)b*131072 + off;
  floatx4 acc0[4] = {}, acc1[4] = {}, s0 = {}, s1 = {};
  const i64 ONES = 0x3838383838383838L;   // fp8 e4m3 1.0 x8
  #define STG_KG(bufi, kk) do{ \
    if (w==0){ gl16(A0g+(kk), lds+(bufi)*2048); gl16(A0g+(kk)+16384, lds+(bufi)*2048+1024); gl16(Bg+(kk), lds+12288+(bufi)*8192); } \
    else if (w==1){ gl16(A1g+(kk), lds+6144+(bufi)*2048); gl16(A1g+(kk)+16384, lds+6144+(bufi)*2048+1024); gl16(Bg+(kk)+16384, lds+12288+(bufi)*8192+1024); } \
    else if (w==2){ gl16(Bg+(kk)+32768, lds+12288+(bufi)*8192+2048); gl16(Bg+(kk)+49152, lds+12288+(bufi)*8192+3072); gl16(Bg+(kk)+65536, lds+12288+(bufi)*8192+4096); } \
    else { gl16(Bg+(kk)+81920, lds+12288+(bufi)*8192+5120); gl16(Bg+(kk)+98304, lds+12288+(bufi)*8192+6144); gl16(Bg+(kk)+114688, lds+12288+(bufi)*8192+7168); } \
  }while(0)
  STG_KG(0, 0);
  STG_KG(1, 64);
  int cur = 0;
  for (int step = 0; step < 16; ++step){
    if (step < 14) {
      int nb = cur + 2; if (nb >= 3) nb -= 3;
      STG_KG(nb, (step+2)*64);
      VM6;
    } else if (step == 14) { VM3; } else { VM0; }
    SBAR; SCHED0;
    const char* A0b = lds + cur*2048;
    const char* A1b = lds + 6144 + cur*2048;
    const char* Bb  = lds + 12288 + cur*8192;
    #pragma unroll
    for (int kf=0; kf<2; kf++){
      i64 a0 = ldA8(A0b, wm*16+lr, kf, lg);
      i64 a1 = ldA8(A1b, wm*16+lr, kf, lg);
      s0 = MFMA8(a0, ONES, s0);
      s1 = MFMA8(a1, ONES, s1);
      #pragma unroll
      for (int nf=0; nf<4; nf++){
        i64 bb = ldA8(Bb, wn*64+nf*16+lr, kf, lg);
        acc0[nf] = MFMA8(a0, bb, acc0[nf]);
        acc1[nf] = MFMA8(a1, bb, acc1[nf]);
      }
    }
    SCHED0; SBAR;
    if (++cur == 3) cur = 0;
  }
  __syncthreads();
  // ---- epilogue: SL[32][392] = [x | Y0 | Y1] bf16 ----
  u16* SL = (u16*)lds;
  u16* SLT = (u16*)(lds + 25088);   // [64][40]
  float d0i[4], d1i[4];
  #pragma unroll
  for (int rr=0; rr<4; rr++){
    d1i[rr] = 1.0f / (s0[rr] + 1.0f);   // adj row sums -> d1
    d0i[rr] = 1.0f / (s1[rr] + 1.0f);   // adj col sums -> d0
  }
  #pragma unroll
  for (int nf = 0; nf < 4; nf++) {
    #pragma unroll
    for (int rr = 0; rr < 4; rr++) {
      int rl = wm*16 + lg*4 + rr;
      int row = mt*32 + rl;
      int col = wn*64 + nf*16 + lr;
      float xv = (col < 64) ? inp[(size_t)(b*1024+row)*64 + col]
                            : hx [(size_t)(b*1024+row)*64 + (col-64)];
      float y0 = (acc0[nf][rr] + xv) * d0i[rr];
      float y1 = (acc1[nf][rr] + xv) * d1i[rr];
      u16 b0v = f2bf(y0), b1v = f2bf(y1);
      SL[rl*392 + col]       = f2bf(xv);
      SL[rl*392 + 128 + col] = b0v;
      SL[rl*392 + 256 + col] = b1v;
      if (col < 64) {
        size_t grow = (size_t)(b*1024 + row)*384;
        XC2[grow + 128 + col] = b0v;
        XC2[grow + 256 + col] = b1v;
      }
    }
  }
  __syncthreads();
  // ---- gates GEMM: 32x384 @ 384x128 (bf16) ----
  floatx4 g[4] = {};
  for (int kk = 0; kk < 384; kk += 32) {
    int ko = kk + lg*8;
    bf16x8 a = ldfrag(&SL[(size_t)(wm*16+lr)*392 + ko]);
    #pragma unroll
    for (int nf = 0; nf < 4; nf++)
      g[nf] = MFMA16(a, ldfrag(WgT + (size_t)(wn*64+nf*16+lr)*384 + ko), g[nf]);
  }
  #pragma unroll
  for (int nf = 0; nf < 4; nf++) {
    #pragma unroll
    for (int rr = 0; rr < 4; rr++) {
      int rl = wm*16 + lg*4 + rr;
      int row = mt*32 + rl;
      int col = wn*64 + nf*16 + lr;
      float pre = g[nf][rr] + bias_g[col];
      float s = 1.0f / (1.0f + __expf(-pre));
      if (col < 64) {          // r gate -> S = r*hx
        float shv = s * hx[(size_t)(b*1024+row)*64 + col];
        u16 bv = f2bf(shv);
        XC2[(size_t)(b*1024+row)*384 + 64 + col] = bv;
        SLT[col*40 + rl] = bv;
      } else {                 // u gate
        uBuf[(size_t)(b*1024+row)*64 + (col-64)] = s;
      }
    }
  }
  __syncthreads();
  // St fp8 writeout (feature-major)
  {
    int c2 = t >> 2, q = t & 3;
    uint4 vv = *(const uint4*)&SLT[c2*40 + q*8];
    u32 arr[4] = {vv.x, vv.y, vv.z, vv.w};
    float f[8];
    #pragma unroll
    for (int e=0;e<8;e++) f[e] = bf2f((u16)(arr[e>>1] >> ((e&1)*16)));
    u32 p0 = pk4(f[0],f[1],f[2],f[3]);
    u32 p1 = pk4(f[4],f[5],f[6],f[7]);
    *(uint2*)(Stf8 + (size_t)b*65536 + (size_t)c2*1024 + mt*32 + q*8) = make_uint2(p0,p1);
  }
  #undef STG_KG
}

// ================ KZ2: fp8 Z diffusion + candidate + GRU ====================
__global__ __launch_bounds__(256) void kz2_cand(
    const u8* __restrict__ adjf8, const u8* __restrict__ adjTf8,
    const u8* __restrict__ Stf8,
    const u16* __restrict__ XC2, const u16* __restrict__ WcT,
    const float* __restrict__ bias_c,
    const float* __restrict__ uBuf, const float* __restrict__ hx,
    float* __restrict__ out){
  __shared__ __align__(16) char lds[25088];  // A0 3x2K | A1 @6144 | B @12288 3x4K
  int bid = ((blockIdx.x & 7)<<6) + (blockIdx.x >> 3);
  int mt = bid & 31, b = bid >> 5;
  int t = threadIdx.x, w = t>>6, l = t&63, lr = l&15, lg = l>>4;
  int wm = w>>1, wn = w&1;
  int gp = (l&7) ^ ((l>>3)&7);
  size_t off = (size_t)(2*(l>>3) + (gp>>2))*1024 + (gp&3)*16;
  const u8* A0g = adjf8  + ((size_t)b<<20) + (size_t)mt*32768 + off;
  const u8* A1g = adjTf8 + ((size_t)b<<20) + (size_t)mt*32768 + off;
  const u8* Bg  = Stf8 + (size_t)b*65536 + off;
  floatx4 z0[2] = {}, z1[2] = {}, s0 = {}, s1 = {};
  const i64 ONES = 0x3838383838383838L;
  #define STG_KZ(bufi, kk) do{ \
    if (w==0){ gl16(A0g+(kk), lds+(bufi)*2048); gl16(A0g+(kk)+16384, lds+(bufi)*2048+1024); } \
    else if (w==1){ gl16(A1g+(kk), lds+6144+(bufi)*2048); gl16(A1g+(kk)+16384, lds+6144+(bufi)*2048+1024); } \
    else if (w==2){ gl16(Bg+(kk), lds+12288+(bufi)*4096); gl16(Bg+(kk)+16384, lds+12288+(bufi)*4096+1024); } \
    else { gl16(Bg+(kk)+32768, lds+12288+(bufi)*4096+2048); gl16(Bg+(kk)+49152, lds+12288+(bufi)*4096+3072); } \
  }while(0)
  STG_KZ(0, 0);
  STG_KZ(1, 64);
  int cur = 0;
  for (int step = 0; step < 16; ++step){
    if (step < 14) {
      int nb = cur + 2; if (nb >= 3) nb -= 3;
      STG_KZ(nb, (step+2)*64);
      VM4;
    } else if (step == 14) { VM2; } else { VM0; }
    SBAR; SCHED0;
    const char* A0b = lds + cur*2048;
    const char* A1b = lds + 6144 + cur*2048;
    const char* Bb  = lds + 12288 + cur*4096;
    #pragma unroll
    for (int kf=0; kf<2; kf++){
      i64 a0 = ldA8(A0b, wm*16+lr, kf, lg);
      i64 a1 = ldA8(A1b, wm*16+lr, kf, lg);
      s0 = MFMA8(a0, ONES, s0);
      s1 = MFMA8(a1, ONES, s1);
      #pragma unroll
      for (int nf=0; nf<2; nf++){
        i64 bb = ldA8(Bb, wn*32+nf*16+lr, kf, lg);
        z0[nf] = MFMA8(a0, bb, z0[nf]);
        z1[nf] = MFMA8(a1, bb, z1[nf]);
      }
    }
    SCHED0; SBAR;
    if (++cur == 3) cur = 0;
  }
  __syncthreads();
  // ---- SL[32][392] = [x|S | Y0inp|Z0 | Y1inp|Z1] ----
  u16* SL = (u16*)lds;
  {
    int rl = t >> 3, s = t & 7;
    size_t grow = (size_t)(b*1024 + mt*32 + rl)*384;
    #pragma unroll
    for (int j = 0; j < 3; j++)
      *(uint4*)&SL[(size_t)rl*392 + s*24 + j*8] =
        *(const uint4*)(XC2 + grow + s*24 + j*8);
    *(uint4*)&SL[(size_t)rl*392 + 256 + s*8] =
      *(const uint4*)(XC2 + grow + 256 + s*8);
  }
  float d0i[4], d1i[4];
  #pragma unroll
  for (int rr=0; rr<4; rr++){
    d1i[rr] = 1.0f / (s0[rr] + 1.0f);
    d0i[rr] = 1.0f / (s1[rr] + 1.0f);
  }
  #pragma unroll
  for (int nf = 0; nf < 2; nf++) {
    #pragma unroll
    for (int rr = 0; rr < 4; rr++) {
      int rl = wm*16 + lg*4 + rr;
      int row = mt*32 + rl;
      int col = wn*32 + nf*16 + lr;
      float sval = bf2f(XC2[(size_t)(b*1024+row)*384 + 64 + col]);
      SL[rl*392 + 192 + col] = f2bf((z0[nf][rr] + sval) * d0i[rr]);
      SL[rl*392 + 320 + col] = f2bf((z1[nf][rr] + sval) * d1i[rr]);
    }
  }
  __syncthreads();
  floatx4 c[2] = {};
  for (int kk = 0; kk < 384; kk += 32) {
    int ko = kk + lg*8;
    bf16x8 a = ldfrag(&SL[(size_t)(wm*16+lr)*392 + ko]);
    #pragma unroll
    for (int nf = 0; nf < 2; nf++)
      c[nf] = MFMA16(a, ldfrag(WcT + (size_t)(wn*32+nf*16+lr)*384 + ko), c[nf]);
  }
  #pragma unroll
  for (int nf = 0; nf < 2; nf++) {
    #pragma unroll
    for (int rr = 0; rr < 4; rr++) {
      int row = mt*32 + wm*16 + lg*4 + rr;
      int col = wn*32 + nf*16 + lr;
      float pre = c[nf][rr] + bias_c[col];
      pre = fminf(fmaxf(pre, -15.f), 15.f);
      float e2 = __expf(2.0f*pre);
      float cv = (e2 - 1.0f) / (e2 + 1.0f);
      float u = uBuf[(size_t)(b*1024+row)*64 + col];
      float h = hx[(size_t)(b*1024+row)*64 + col];
      out[(size_t)(b*1024+row)*64 + col] = u*h + (1.0f - u)*cv;
    }
  }
  #undef STG_KZ
}

extern "C" void kernel_launch(void* const* d_in, const int* in_sizes, int n_in,
                              void* d_out, int out_size, void* d_ws, size_t ws_size,
                              hipStream_t stream) {
  (void)in_sizes; (void)n_in; (void)out_size; (void)ws_size;
  const float* inp = (const float*)d_in[0];
  const float* hx  = (const float*)d_in[1];
  const float* adj = (const float*)d_in[2];
  const float* W0  = (const float*)d_in[3];
  const float* b0  = (const float*)d_in[4];
  const float* W1  = (const float*)d_in[5];
  const float* b1  = (const float*)d_in[6];
  const float* Wc0 = (const float*)d_in[7];
  const float* bc0 = (const float*)d_in[8];
  const float* Wc1 = (const float*)d_in[9];
  const float* bc1 = (const float*)d_in[10];
  float* out = (float*)d_out;
  char* ws = (char*)d_ws;

  u8* adjf8   = (u8*)(ws + 0);                 // 16777216
  u8* adjTf8  = (u8*)(ws + 16777216);          // 16777216
  u8* Xtf8    = (u8*)(ws + 33554432);          // 2097152
  u16* XC2    = (u16*)(ws + 35651584);         // 12582912
  u8* Stf8    = (u8*)(ws + 48234496);          // 1048576
  float* uBuf = (float*)(ws + 49283072);       // 4194304
  u16* WgT    = (u16*)(ws + 53477376);         // 98304
  u16* WcT    = (u16*)(ws + 53575680);         // 49152
  float* bias_g = (float*)(ws + 53624832);     // 512
  float* bias_c = (float*)(ws + 53625344);     // 256

  hipLaunchKernelGGL(kp3_prep, dim3(1568), dim3(256), 0, stream,
                     inp, hx, adj, W0, b0, W1, b1, Wc0, bc0, Wc1, bc1,
                     WgT, WcT, bias_g, bias_c, adjf8, adjTf8, Xtf8, XC2);
  hipLaunchKernelGGL(kg2_gates, dim3(512), dim3(256), 0, stream,
                     adjf8, adjTf8, Xtf8, inp, hx, WgT, bias_g, XC2, Stf8, uBuf);
  hipLaunchKernelGGL(kz2_cand, dim3(512), dim3(256), 0, stream,
                     adjf8, adjTf8, Stf8, XC2, WcT, bias_c, uBuf, hx, out);
}